// Round 3
// baseline (23580.493 us; speedup 1.0000x reference)
//
#include <hip/hip_runtime.h>

#define IN_DIM 32
#define HID 64
#define LN_EPS 1e-5f

__global__ __launch_bounds__(256) void zero16(uint4* __restrict__ p, int n16) {
    const int i = blockIdx.x * 256 + threadIdx.x;
    if (i < n16) p[i] = make_uint4(0u, 0u, 0u, 0u);
}

__global__ __launch_bounds__(256) void mlp_ln_scatter(
    const float* __restrict__ x,     // [E,32] f32
    const int* __restrict__ idx,     // [E,2] int32 (or int64 — sniffed)
    const float* __restrict__ W1, const float* __restrict__ b1,
    const float* __restrict__ W2, const float* __restrict__ b2,
    const float* __restrict__ W3, const float* __restrict__ b3,
    const float* __restrict__ W4, const float* __restrict__ b4,
    const float* __restrict__ gamma, const float* __restrict__ beta,
    float* __restrict__ out_edge,    // [E,64] f32
    float* __restrict__ node_acc,    // [N,64] f32 (d_out node region, pre-zeroed)
    int E, int N)
{
    __shared__ float sW1[IN_DIM * HID];   // 8 KB
    __shared__ float sW2[HID * HID];      // 16 KB
    __shared__ float sW3[HID * HID];
    __shared__ float sW4[HID * HID];
    __shared__ float sB[6 * HID];         // b1,b2,b3,b4,gamma,beta

    const int tid = threadIdx.x;
    {   // stage weights (f32, vectorized)
        const float4* W1v = reinterpret_cast<const float4*>(W1);
        float4* s1 = reinterpret_cast<float4*>(sW1);
        for (int i = tid; i < IN_DIM * HID / 4; i += 256) s1[i] = W1v[i];
        const float4* W2v = reinterpret_cast<const float4*>(W2);
        const float4* W3v = reinterpret_cast<const float4*>(W3);
        const float4* W4v = reinterpret_cast<const float4*>(W4);
        float4* s2 = reinterpret_cast<float4*>(sW2);
        float4* s3 = reinterpret_cast<float4*>(sW3);
        float4* s4 = reinterpret_cast<float4*>(sW4);
        for (int i = tid; i < HID * HID / 4; i += 256) {
            s2[i] = W2v[i]; s3[i] = W3v[i]; s4[i] = W4v[i];
        }
        if (tid < HID) {
            sB[0 * HID + tid] = b1[tid];
            sB[1 * HID + tid] = b2[tid];
            sB[2 * HID + tid] = b3[tid];
            sB[3 * HID + tid] = b4[tid];
            sB[4 * HID + tid] = gamma[tid];
            sB[5 * HID + tid] = beta[tid];
        }
    }
    __syncthreads();

    const int e = blockIdx.x * 256 + tid;
    if (e >= E) return;

    // ---- sniff edge_index dtype: int64 hi-words are zero at odd positions ----
    int zc = 0;
    #pragma unroll
    for (int t = 0; t < 64; ++t) zc += (idx[2 * t + 1] == 0) ? 1 : 0;
    const bool idx64 = (zc >= 32);

    // ---- load input row (32 f32 = 128B, 8x float4) ----
    float h0[IN_DIM];
    {
        const float4* xv = reinterpret_cast<const float4*>(x + (size_t)e * IN_DIM);
        #pragma unroll
        for (int c = 0; c < 8; ++c) {
            const float4 v = xv[c];
            h0[c * 4 + 0] = v.x; h0[c * 4 + 1] = v.y;
            h0[c * 4 + 2] = v.z; h0[c * 4 + 3] = v.w;
        }
    }

    float a[HID], h[HID];

    // ---- layer 1: 32 -> 64, ReLU ----
    #pragma unroll
    for (int j = 0; j < HID; ++j) a[j] = sB[j];
    #pragma unroll
    for (int k = 0; k < IN_DIM; ++k) {
        const float hk = h0[k];
        #pragma unroll
        for (int j = 0; j < HID; ++j) a[j] = fmaf(hk, sW1[k * HID + j], a[j]);
    }
    #pragma unroll
    for (int j = 0; j < HID; ++j) h[j] = a[j] > 0.f ? a[j] : 0.f;

    // ---- layer 2: 64 -> 64, ReLU ----
    #pragma unroll
    for (int j = 0; j < HID; ++j) a[j] = sB[HID + j];
    #pragma unroll
    for (int k = 0; k < HID; ++k) {
        const float hk = h[k];
        #pragma unroll
        for (int j = 0; j < HID; ++j) a[j] = fmaf(hk, sW2[k * HID + j], a[j]);
    }
    #pragma unroll
    for (int j = 0; j < HID; ++j) h[j] = a[j] > 0.f ? a[j] : 0.f;

    // ---- layer 3: 64 -> 64, ReLU ----
    #pragma unroll
    for (int j = 0; j < HID; ++j) a[j] = sB[2 * HID + j];
    #pragma unroll
    for (int k = 0; k < HID; ++k) {
        const float hk = h[k];
        #pragma unroll
        for (int j = 0; j < HID; ++j) a[j] = fmaf(hk, sW3[k * HID + j], a[j]);
    }
    #pragma unroll
    for (int j = 0; j < HID; ++j) h[j] = a[j] > 0.f ? a[j] : 0.f;

    // ---- layer 4: 64 -> 64, no ReLU ----
    #pragma unroll
    for (int j = 0; j < HID; ++j) a[j] = sB[3 * HID + j];
    #pragma unroll
    for (int k = 0; k < HID; ++k) {
        const float hk = h[k];
        #pragma unroll
        for (int j = 0; j < HID; ++j) a[j] = fmaf(hk, sW4[k * HID + j], a[j]);
    }

    // ---- LayerNorm over feature dim (in registers) ----
    float s = 0.f;
    #pragma unroll
    for (int j = 0; j < HID; ++j) s += a[j];
    const float mu = s * (1.0f / HID);
    float s2 = 0.f;
    #pragma unroll
    for (int j = 0; j < HID; ++j) { const float d = a[j] - mu; s2 += d * d; }
    const float inv = rsqrtf(s2 * (1.0f / HID) + LN_EPS);
    #pragma unroll
    for (int j = 0; j < HID; ++j)
        a[j] = sB[4 * HID + j] * ((a[j] - mu) * inv) + sB[5 * HID + j];

    // ---- write x_edge1 row (64 f32 = 256B, 16x float4) ----
    {
        float4* oe = reinterpret_cast<float4*>(out_edge + (size_t)e * HID);
        #pragma unroll
        for (int c = 0; c < 16; ++c)
            oe[c] = make_float4(a[c * 4 + 0], a[c * 4 + 1], a[c * 4 + 2], a[c * 4 + 3]);
    }

    // ---- double scatter-add into node region of d_out (f32 atomics) ----
    int na, nb;
    if (idx64) {
        na = idx[4 * (size_t)e];
        nb = idx[4 * (size_t)e + 2];
    } else {
        na = idx[2 * (size_t)e];
        nb = idx[2 * (size_t)e + 1];
    }
    na = min(max(na, 0), N - 1);
    nb = min(max(nb, 0), N - 1);
    float* pa = node_acc + (size_t)na * HID;
    float* pb = node_acc + (size_t)nb * HID;
    #pragma unroll
    for (int j = 0; j < HID; ++j) {
        unsafeAtomicAdd(pa + j, a[j]);
        unsafeAtomicAdd(pb + j, a[j]);
    }
}

extern "C" void kernel_launch(void* const* d_in, const int* in_sizes, int n_in,
                              void* d_out, int out_size, void* d_ws, size_t ws_size,
                              hipStream_t stream) {
    const float* x     = (const float*)d_in[0];
    const int*   idx   = (const int*)d_in[1];
    // d_in[2] = num_nodes device scalar; derive N from sizes instead.
    const float* W1    = (const float*)d_in[3];
    const float* b1    = (const float*)d_in[4];
    const float* W2    = (const float*)d_in[5];
    const float* b2    = (const float*)d_in[6];
    const float* W3    = (const float*)d_in[7];
    const float* b3    = (const float*)d_in[8];
    const float* W4    = (const float*)d_in[9];
    const float* b4    = (const float*)d_in[10];
    const float* gamma = (const float*)d_in[11];
    const float* beta  = (const float*)d_in[12];

    const int E = in_sizes[0] / IN_DIM;        // element counts are dtype-independent
    const int N = out_size / HID - E;          // out = [N*64 | E*64] f32

    float* out_node = (float*)d_out;                 // [N,64] f32
    float* out_edge = out_node + (size_t)N * HID;    // [E,64] f32

    // zero the node accumulator region (harness poisons, never restores)
    const int n16 = (int)(((size_t)N * HID * sizeof(float)) / 16);
    zero16<<<(n16 + 255) / 256, 256, 0, stream>>>((uint4*)out_node, n16);

    const int grid = (E + 255) / 256;
    mlp_ln_scatter<<<grid, 256, 0, stream>>>(x, idx, W1, b1, W2, b2, W3, b3,
                                             W4, b4, gamma, beta,
                                             out_edge, out_node, E, N);
}

// Round 4
// 13018.675 us; speedup vs baseline: 1.8113x; 1.8113x over previous
//
#include <hip/hip_runtime.h>

#define IN_DIM 32
#define HID 64
#define LN_EPS 1e-5f

__global__ __launch_bounds__(256) void zero_i32(int* __restrict__ p, int n) {
    const int i = blockIdx.x * 256 + threadIdx.x;
    if (i < n) p[i] = 0;
}

__global__ __launch_bounds__(256) void zero16(uint4* __restrict__ p, int n16) {
    const int i = blockIdx.x * 256 + threadIdx.x;
    if (i < n16) p[i] = make_uint4(0u, 0u, 0u, 0u);
}

static __device__ __forceinline__ bool sniff_idx64(const int* idx) {
    int zc = 0;
    #pragma unroll
    for (int t = 0; t < 8; ++t) zc += (idx[2 * t + 1] == 0) ? 1 : 0;
    return zc >= 7;  // int64 hi-words are all zero (nodes < 2^31)
}

// count endpoint occurrences: cnt[node]++ for both endpoints of every edge
__global__ __launch_bounds__(256) void count_deg(
    const int* __restrict__ idx, int* __restrict__ cnt, int E, int N)
{
    const bool idx64 = sniff_idx64(idx);
    const int i = blockIdx.x * 256 + threadIdx.x;   // endpoint slot, i < 2E
    if (i >= 2 * E) return;
    int node = idx64 ? idx[2 * (size_t)i] : idx[i];
    node = min(max(node, 0), N - 1);
    atomicAdd(&cnt[node], 1);
}

// in-place exclusive scan over a[0..n): single block, 1024 threads
__global__ __launch_bounds__(1024) void scan_excl(int* __restrict__ a, int n) {
    __shared__ int lds[1024];
    const int t = threadIdx.x;
    const int L = (n + 1023) >> 10;
    const int lo = t * L, hi = min(n, lo + L);
    int s = 0;
    for (int i = lo; i < hi; ++i) s += a[i];
    lds[t] = s;
    __syncthreads();
    #pragma unroll
    for (int d = 1; d < 1024; d <<= 1) {
        const int v = (t >= d) ? lds[t - d] : 0;
        __syncthreads();
        lds[t] += v;
        __syncthreads();
    }
    int run = lds[t] - s;   // exclusive base of this thread's chunk
    for (int i = lo; i < hi; ++i) { const int c = a[i]; a[i] = run; run += c; }
}

// fill edge lists; off[] starts as segment starts, ends as segment ENDS
__global__ __launch_bounds__(256) void fill_csr(
    const int* __restrict__ idx, int* __restrict__ off,
    int* __restrict__ elist, int E, int N)
{
    const bool idx64 = sniff_idx64(idx);
    const int e = blockIdx.x * 256 + threadIdx.x;
    if (e >= E) return;
    int na, nb;
    if (idx64) { na = idx[4 * (size_t)e]; nb = idx[4 * (size_t)e + 2]; }
    else       { na = idx[2 * (size_t)e]; nb = idx[2 * (size_t)e + 1]; }
    na = min(max(na, 0), N - 1);
    nb = min(max(nb, 0), N - 1);
    const int pa = atomicAdd(&off[na], 1);
    elist[pa] = e;
    const int pb = atomicAdd(&off[nb], 1);
    elist[pb] = e;
}

// SCATTER=1: legacy fallback (atomic adds into node region). SCATTER=0: edge-only.
template <int SCATTER>
__global__ __launch_bounds__(256) void mlp_ln(
    const float* __restrict__ x,     // [E,32]
    const int* __restrict__ idx,     // only used when SCATTER=1
    const float* __restrict__ W1, const float* __restrict__ b1,
    const float* __restrict__ W2, const float* __restrict__ b2,
    const float* __restrict__ W3, const float* __restrict__ b3,
    const float* __restrict__ W4, const float* __restrict__ b4,
    const float* __restrict__ gamma, const float* __restrict__ beta,
    float* __restrict__ out_edge,    // [E,64]
    float* __restrict__ node_acc,    // only used when SCATTER=1
    int E, int N)
{
    __shared__ float sW1[IN_DIM * HID];
    __shared__ float sW2[HID * HID];
    __shared__ float sW3[HID * HID];
    __shared__ float sW4[HID * HID];
    __shared__ float sB[6 * HID];

    const int tid = threadIdx.x;
    {
        const float4* W1v = reinterpret_cast<const float4*>(W1);
        float4* s1 = reinterpret_cast<float4*>(sW1);
        for (int i = tid; i < IN_DIM * HID / 4; i += 256) s1[i] = W1v[i];
        const float4* W2v = reinterpret_cast<const float4*>(W2);
        const float4* W3v = reinterpret_cast<const float4*>(W3);
        const float4* W4v = reinterpret_cast<const float4*>(W4);
        float4* s2 = reinterpret_cast<float4*>(sW2);
        float4* s3 = reinterpret_cast<float4*>(sW3);
        float4* s4 = reinterpret_cast<float4*>(sW4);
        for (int i = tid; i < HID * HID / 4; i += 256) {
            s2[i] = W2v[i]; s3[i] = W3v[i]; s4[i] = W4v[i];
        }
        if (tid < HID) {
            sB[0 * HID + tid] = b1[tid];
            sB[1 * HID + tid] = b2[tid];
            sB[2 * HID + tid] = b3[tid];
            sB[3 * HID + tid] = b4[tid];
            sB[4 * HID + tid] = gamma[tid];
            sB[5 * HID + tid] = beta[tid];
        }
    }
    __syncthreads();

    const int e = blockIdx.x * 256 + tid;
    if (e >= E) return;

    float h0[IN_DIM];
    {
        const float4* xv = reinterpret_cast<const float4*>(x + (size_t)e * IN_DIM);
        #pragma unroll
        for (int c = 0; c < 8; ++c) {
            const float4 v = xv[c];
            h0[c * 4 + 0] = v.x; h0[c * 4 + 1] = v.y;
            h0[c * 4 + 2] = v.z; h0[c * 4 + 3] = v.w;
        }
    }

    float a[HID], h[HID];

    #pragma unroll
    for (int j = 0; j < HID; ++j) a[j] = sB[j];
    #pragma unroll
    for (int k = 0; k < IN_DIM; ++k) {
        const float hk = h0[k];
        #pragma unroll
        for (int j = 0; j < HID; ++j) a[j] = fmaf(hk, sW1[k * HID + j], a[j]);
    }
    #pragma unroll
    for (int j = 0; j < HID; ++j) h[j] = a[j] > 0.f ? a[j] : 0.f;

    #pragma unroll
    for (int j = 0; j < HID; ++j) a[j] = sB[HID + j];
    #pragma unroll
    for (int k = 0; k < HID; ++k) {
        const float hk = h[k];
        #pragma unroll
        for (int j = 0; j < HID; ++j) a[j] = fmaf(hk, sW2[k * HID + j], a[j]);
    }
    #pragma unroll
    for (int j = 0; j < HID; ++j) h[j] = a[j] > 0.f ? a[j] : 0.f;

    #pragma unroll
    for (int j = 0; j < HID; ++j) a[j] = sB[2 * HID + j];
    #pragma unroll
    for (int k = 0; k < HID; ++k) {
        const float hk = h[k];
        #pragma unroll
        for (int j = 0; j < HID; ++j) a[j] = fmaf(hk, sW3[k * HID + j], a[j]);
    }
    #pragma unroll
    for (int j = 0; j < HID; ++j) h[j] = a[j] > 0.f ? a[j] : 0.f;

    #pragma unroll
    for (int j = 0; j < HID; ++j) a[j] = sB[3 * HID + j];
    #pragma unroll
    for (int k = 0; k < HID; ++k) {
        const float hk = h[k];
        #pragma unroll
        for (int j = 0; j < HID; ++j) a[j] = fmaf(hk, sW4[k * HID + j], a[j]);
    }

    float s = 0.f;
    #pragma unroll
    for (int j = 0; j < HID; ++j) s += a[j];
    const float mu = s * (1.0f / HID);
    float s2 = 0.f;
    #pragma unroll
    for (int j = 0; j < HID; ++j) { const float d = a[j] - mu; s2 += d * d; }
    const float inv = rsqrtf(s2 * (1.0f / HID) + LN_EPS);
    #pragma unroll
    for (int j = 0; j < HID; ++j)
        a[j] = sB[4 * HID + j] * ((a[j] - mu) * inv) + sB[5 * HID + j];

    {
        float4* oe = reinterpret_cast<float4*>(out_edge + (size_t)e * HID);
        #pragma unroll
        for (int c = 0; c < 16; ++c)
            oe[c] = make_float4(a[c * 4 + 0], a[c * 4 + 1], a[c * 4 + 2], a[c * 4 + 3]);
    }

    if (SCATTER) {
        const bool idx64 = sniff_idx64(idx);
        int na, nb;
        if (idx64) { na = idx[4 * (size_t)e]; nb = idx[4 * (size_t)e + 2]; }
        else       { na = idx[2 * (size_t)e]; nb = idx[2 * (size_t)e + 1]; }
        na = min(max(na, 0), N - 1);
        nb = min(max(nb, 0), N - 1);
        float* pa = node_acc + (size_t)na * HID;
        float* pb = node_acc + (size_t)nb * HID;
        #pragma unroll
        for (int j = 0; j < HID; ++j) {
            unsafeAtomicAdd(pa + j, a[j]);
            unsafeAtomicAdd(pb + j, a[j]);
        }
    }
}

// one 64-lane wave per node; lane = feature index
__global__ __launch_bounds__(256) void gather_nodes(
    const int* __restrict__ off,     // post-fill: off[n] = END of segment n
    const int* __restrict__ elist,
    const float* __restrict__ edge_feat,  // [E,64]
    float* __restrict__ out_node, int N)
{
    const int wv = (blockIdx.x * 256 + threadIdx.x) >> 6;
    const int lane = threadIdx.x & 63;
    if (wv >= N) return;
    const int start = (wv == 0) ? 0 : off[wv - 1];
    const int end = off[wv];
    float s = 0.f;
    int i = start;
    for (; i + 4 <= end; i += 4) {
        const int e0 = elist[i], e1 = elist[i + 1], e2 = elist[i + 2], e3 = elist[i + 3];
        const float v0 = edge_feat[(size_t)e0 * HID + lane];
        const float v1 = edge_feat[(size_t)e1 * HID + lane];
        const float v2 = edge_feat[(size_t)e2 * HID + lane];
        const float v3 = edge_feat[(size_t)e3 * HID + lane];
        s += v0; s += v1; s += v2; s += v3;
    }
    for (; i < end; ++i) s += edge_feat[(size_t)elist[i] * HID + lane];
    out_node[(size_t)wv * HID + lane] = s;
}

extern "C" void kernel_launch(void* const* d_in, const int* in_sizes, int n_in,
                              void* d_out, int out_size, void* d_ws, size_t ws_size,
                              hipStream_t stream) {
    const float* x     = (const float*)d_in[0];
    const int*   idx   = (const int*)d_in[1];
    const float* W1    = (const float*)d_in[3];
    const float* b1    = (const float*)d_in[4];
    const float* W2    = (const float*)d_in[5];
    const float* b2    = (const float*)d_in[6];
    const float* W3    = (const float*)d_in[7];
    const float* b3    = (const float*)d_in[8];
    const float* W4    = (const float*)d_in[9];
    const float* b4    = (const float*)d_in[10];
    const float* gamma = (const float*)d_in[11];
    const float* beta  = (const float*)d_in[12];

    const int E = in_sizes[0] / IN_DIM;
    const int N = out_size / HID - E;

    float* out_node = (float*)d_out;
    float* out_edge = out_node + (size_t)N * HID;

    const size_t need = (size_t)N * sizeof(int) + (size_t)2 * E * sizeof(int);
    const int grid_e = (E + 255) / 256;

    if (ws_size >= need) {
        int* off   = (int*)d_ws;        // [N]
        int* elist = off + N;           // [2E]

        zero_i32<<<(N + 255) / 256, 256, 0, stream>>>(off, N);
        count_deg<<<(2 * E + 255) / 256, 256, 0, stream>>>(idx, off, E, N);
        scan_excl<<<1, 1024, 0, stream>>>(off, N);
        fill_csr<<<grid_e, 256, 0, stream>>>(idx, off, elist, E, N);
        mlp_ln<0><<<grid_e, 256, 0, stream>>>(x, idx, W1, b1, W2, b2, W3, b3,
                                              W4, b4, gamma, beta,
                                              out_edge, out_node, E, N);
        gather_nodes<<<(N * 64 + 255) / 256, 256, 0, stream>>>(
            off, elist, out_edge, out_node, N);
    } else {
        // fallback: round-3 atomic path (known-passing)
        const int n16 = (int)(((size_t)N * HID * sizeof(float)) / 16);
        zero16<<<(n16 + 255) / 256, 256, 0, stream>>>((uint4*)out_node, n16);
        mlp_ln<1><<<grid_e, 256, 0, stream>>>(x, idx, W1, b1, W2, b2, W3, b3,
                                              W4, b4, gamma, beta,
                                              out_edge, out_node, E, N);
    }
}

// Round 5
// 1712.697 us; speedup vs baseline: 13.7680x; 7.6013x over previous
//
#include <hip/hip_runtime.h>

#define IN_DIM 32
#define HID 64
#define LN_EPS 1e-5f

typedef unsigned short ush;
typedef __attribute__((ext_vector_type(8))) short bf16x8;
typedef __attribute__((ext_vector_type(4))) float f32x4;

static __device__ __forceinline__ float b2f(ush u) {
    union { unsigned int i; float f; } v; v.i = ((unsigned int)u) << 16; return v.f;
}
static __device__ __forceinline__ ush f2b(float f) {
    union { float f; unsigned int i; } v; v.f = f;
    unsigned int x = v.i;
    return (ush)((x + 0x7fffu + ((x >> 16) & 1u)) >> 16);  // RNE
}

__global__ __launch_bounds__(256) void zero_i32(int* __restrict__ p, int n) {
    const int i = blockIdx.x * 256 + threadIdx.x;
    if (i < n) p[i] = 0;
}

__global__ __launch_bounds__(256) void zero16(uint4* __restrict__ p, int n16) {
    const int i = blockIdx.x * 256 + threadIdx.x;
    if (i < n16) p[i] = make_uint4(0u, 0u, 0u, 0u);
}

static __device__ __forceinline__ bool sniff_idx64(const int* idx) {
    int zc = 0;
    #pragma unroll
    for (int t = 0; t < 8; ++t) zc += (idx[2 * t + 1] == 0) ? 1 : 0;
    return zc >= 7;
}

__global__ __launch_bounds__(256) void count_deg(
    const int* __restrict__ idx, int* __restrict__ cnt, int E, int N)
{
    const bool idx64 = sniff_idx64(idx);
    const int i = blockIdx.x * 256 + threadIdx.x;
    if (i >= 2 * E) return;
    int node = idx64 ? idx[2 * (size_t)i] : idx[i];
    node = min(max(node, 0), N - 1);
    atomicAdd(&cnt[node], 1);
}

__global__ __launch_bounds__(1024) void scan_excl(int* __restrict__ a, int n) {
    __shared__ int lds[1024];
    const int t = threadIdx.x;
    const int L = (n + 1023) >> 10;
    const int lo = t * L, hi = min(n, lo + L);
    int s = 0;
    for (int i = lo; i < hi; ++i) s += a[i];
    lds[t] = s;
    __syncthreads();
    #pragma unroll
    for (int d = 1; d < 1024; d <<= 1) {
        const int v = (t >= d) ? lds[t - d] : 0;
        __syncthreads();
        lds[t] += v;
        __syncthreads();
    }
    int run = lds[t] - s;
    for (int i = lo; i < hi; ++i) { const int c = a[i]; a[i] = run; run += c; }
}

__global__ __launch_bounds__(256) void fill_csr(
    const int* __restrict__ idx, int* __restrict__ off,
    int* __restrict__ elist, int E, int N)
{
    const bool idx64 = sniff_idx64(idx);
    const int e = blockIdx.x * 256 + threadIdx.x;
    if (e >= E) return;
    int na, nb;
    if (idx64) { na = idx[4 * (size_t)e]; nb = idx[4 * (size_t)e + 2]; }
    else       { na = idx[2 * (size_t)e]; nb = idx[2 * (size_t)e + 1]; }
    na = min(max(na, 0), N - 1);
    nb = min(max(nb, 0), N - 1);
    const int pa = atomicAdd(&off[na], 1);
    elist[pa] = e;
    const int pb = atomicAdd(&off[nb], 1);
    elist[pb] = e;
}

// ---------------- weight packing into B-fragment order ----------------
// Per matrix: element i = (f*64 + l)*8 + e, f = kc*4 + ct:
//   pack[base+i] = bf16( W[kc*32 + (l>>4)*8 + e][ct*16 + (l&15)] )
// W1: base 0 (2048), W2: 2048 (4096), W3: 6144, W4: 10240. Total 14336 bf16.
__global__ __launch_bounds__(256) void pack_weights(
    const float* __restrict__ W1, const float* __restrict__ W2,
    const float* __restrict__ W3, const float* __restrict__ W4,
    ush* __restrict__ pack)
{
    const int i = blockIdx.x * 256 + threadIdx.x;
    if (i >= 14336) return;
    const float* W; int base;
    if (i < 2048)       { W = W1; base = 0; }
    else if (i < 6144)  { W = W2; base = 2048; }
    else if (i < 10240) { W = W3; base = 6144; }
    else                { W = W4; base = 10240; }
    const int j = i - base;
    const int e = j & 7, l = (j >> 3) & 63, f = j >> 9;
    const int ct = f & 3, kc = f >> 2;
    const int k = kc * 32 + ((l >> 4) << 3) + e;
    const int col = ct * 16 + (l & 15);
    pack[i] = f2b(W[k * HID + col]);
}

// ---------------- MFMA MLP + LayerNorm ----------------
// Block: 256 thr = 4 waves; each wave: 2 strips of 16 edges (32 edges/wave,
// 128 edges/block). A-frag: lane l -> row (l&15), k = 8*(l>>4)+e.
// B-frag (packed): lane l -> k = kc*32+8*(l>>4)+e, col = ct*16+(l&15).
// C/D: col = lane&15, row = 4*(lane>>4)+reg.
__global__ __launch_bounds__(256, 2) void mlp_ln_mfma(
    const float* __restrict__ x,       // [E,32] f32
    const ush* __restrict__ packW,     // 14336 bf16
    const float* __restrict__ b1, const float* __restrict__ b2,
    const float* __restrict__ b3, const float* __restrict__ b4,
    const float* __restrict__ gamma, const float* __restrict__ beta,
    float* __restrict__ out_edge,      // [E,64] f32
    int E)
{
    __shared__ float sB[6 * HID];
    __shared__ __align__(16) ush hbuf[4][16 * 72];  // per-wave strip, 144B row stride

    const int tid = threadIdx.x;
    const int wave = tid >> 6, lane = tid & 63;
    if (tid < HID) {
        sB[tid]           = b1[tid];
        sB[HID + tid]     = b2[tid];
        sB[2 * HID + tid] = b3[tid];
        sB[3 * HID + tid] = b4[tid];
        sB[4 * HID + tid] = gamma[tid];
        sB[5 * HID + tid] = beta[tid];
    }
    __syncthreads();

    // load all B-fragments into registers (L2-resident, coalesced 16B/lane)
    const bf16x8* pw = (const bf16x8*)packW;
    bf16x8 w1[4], w2[8], w3[8], w4[8];
    #pragma unroll
    for (int f = 0; f < 4; ++f) w1[f] = pw[f * 64 + lane];
    #pragma unroll
    for (int f = 0; f < 8; ++f) w2[f] = pw[256 + f * 64 + lane];
    #pragma unroll
    for (int f = 0; f < 8; ++f) w3[f] = pw[768 + f * 64 + lane];
    #pragma unroll
    for (int f = 0; f < 8; ++f) w4[f] = pw[1280 + f * 64 + lane];

    ush* hb = &hbuf[wave][0];
    const int l15 = lane & 15, lg = lane >> 4;

    for (int s = 0; s < 2; ++s) {
        const int rowBase = blockIdx.x * 128 + wave * 32 + s * 16;

        // ---- layer-1 A-frag direct from global x (f32 -> bf16) ----
        const int rr = min(rowBase + l15, E - 1);
        const float4* xp = (const float4*)(x + (size_t)rr * IN_DIM + lg * 8);
        const float4 xa = xp[0], xb = xp[1];
        bf16x8 aL1;
        aL1[0] = (short)f2b(xa.x); aL1[1] = (short)f2b(xa.y);
        aL1[2] = (short)f2b(xa.z); aL1[3] = (short)f2b(xa.w);
        aL1[4] = (short)f2b(xb.x); aL1[5] = (short)f2b(xb.y);
        aL1[6] = (short)f2b(xb.z); aL1[7] = (short)f2b(xb.w);

        f32x4 acc[4];

        // ---- layer 1 (K=32) ----
        #pragma unroll
        for (int ct = 0; ct < 4; ++ct) {
            const float bv = sB[0 * HID + ct * 16 + l15];
            f32x4 c = {bv, bv, bv, bv};
            c = __builtin_amdgcn_mfma_f32_16x16x32_bf16(aL1, w1[ct], c, 0, 0, 0);
            acc[ct] = c;
        }

        // relu + write activation strip to LDS (bf16)
        #pragma unroll
        for (int ct = 0; ct < 4; ++ct)
            #pragma unroll
            for (int r = 0; r < 4; ++r) {
                float v = acc[ct][r]; v = v > 0.f ? v : 0.f;
                hb[(lg * 4 + r) * 72 + ct * 16 + l15] = f2b(v);
            }

        #define LAYER(WARR, BIDX, RELU_) do {                                   \
            const bf16x8 a0 = *(const bf16x8*)&hb[l15 * 72 + 0 * 32 + lg * 8];  \
            const bf16x8 a1 = *(const bf16x8*)&hb[l15 * 72 + 1 * 32 + lg * 8];  \
            _Pragma("unroll")                                                   \
            for (int ct = 0; ct < 4; ++ct) {                                    \
                const float bv = sB[(BIDX) * HID + ct * 16 + l15];              \
                f32x4 c = {bv, bv, bv, bv};                                     \
                c = __builtin_amdgcn_mfma_f32_16x16x32_bf16(a0, WARR[ct], c, 0, 0, 0);      \
                c = __builtin_amdgcn_mfma_f32_16x16x32_bf16(a1, WARR[4 + ct], c, 0, 0, 0);  \
                acc[ct] = c;                                                    \
            }                                                                   \
            if (RELU_) {                                                        \
                _Pragma("unroll")                                               \
                for (int ct = 0; ct < 4; ++ct)                                  \
                    _Pragma("unroll")                                           \
                    for (int r = 0; r < 4; ++r) {                               \
                        float v = acc[ct][r]; v = v > 0.f ? v : 0.f;            \
                        hb[(lg * 4 + r) * 72 + ct * 16 + l15] = f2b(v);         \
                    }                                                           \
            }                                                                   \
        } while (0)

        LAYER(w2, 1, 1);
        LAYER(w3, 2, 1);
        LAYER(w4, 3, 0);
        #undef LAYER

        // ---- LayerNorm in-register: row r lives in the 16-lane group lg ----
        float s1[4], s2[4];
        #pragma unroll
        for (int r = 0; r < 4; ++r) {
            float a = acc[0][r] + acc[1][r] + acc[2][r] + acc[3][r];
            float q = acc[0][r] * acc[0][r] + acc[1][r] * acc[1][r]
                    + acc[2][r] * acc[2][r] + acc[3][r] * acc[3][r];
            #pragma unroll
            for (int m = 1; m < 16; m <<= 1) {
                a += __shfl_xor(a, m, 64);
                q += __shfl_xor(q, m, 64);
            }
            s1[r] = a; s2[r] = q;
        }

        #pragma unroll
        for (int r = 0; r < 4; ++r) {
            const float mu = s1[r] * (1.0f / HID);
            const float varr = fmaxf(s2[r] * (1.0f / HID) - mu * mu, 0.f);
            const float inv = rsqrtf(varr + LN_EPS);
            const int row = rowBase + lg * 4 + r;
            if (row < E) {
                float* op = out_edge + (size_t)row * HID;
                #pragma unroll
                for (int ct = 0; ct < 4; ++ct) {
                    const float g = sB[4 * HID + ct * 16 + l15];
                    const float bt = sB[5 * HID + ct * 16 + l15];
                    op[ct * 16 + l15] = g * (acc[ct][r] - mu) * inv + bt;
                }
            }
        }
    }
}

// ---------------- fallback: round-3 VALU kernel with atomics ----------------
__global__ __launch_bounds__(256) void mlp_ln_scatter_fb(
    const float* __restrict__ x, const int* __restrict__ idx,
    const float* __restrict__ W1, const float* __restrict__ b1,
    const float* __restrict__ W2, const float* __restrict__ b2,
    const float* __restrict__ W3, const float* __restrict__ b3,
    const float* __restrict__ W4, const float* __restrict__ b4,
    const float* __restrict__ gamma, const float* __restrict__ beta,
    float* __restrict__ out_edge, float* __restrict__ node_acc, int E, int N)
{
    __shared__ float sW1[IN_DIM * HID];
    __shared__ float sW2[HID * HID];
    __shared__ float sW3[HID * HID];
    __shared__ float sW4[HID * HID];
    __shared__ float sB[6 * HID];
    const int tid = threadIdx.x;
    {
        const float4* W1v = (const float4*)W1;
        float4* s1 = (float4*)sW1;
        for (int i = tid; i < IN_DIM * HID / 4; i += 256) s1[i] = W1v[i];
        const float4* W2v = (const float4*)W2;
        const float4* W3v = (const float4*)W3;
        const float4* W4v = (const float4*)W4;
        float4* s2 = (float4*)sW2; float4* s3 = (float4*)sW3; float4* s4 = (float4*)sW4;
        for (int i = tid; i < HID * HID / 4; i += 256) { s2[i] = W2v[i]; s3[i] = W3v[i]; s4[i] = W4v[i]; }
        if (tid < HID) {
            sB[tid] = b1[tid]; sB[HID + tid] = b2[tid]; sB[2 * HID + tid] = b3[tid];
            sB[3 * HID + tid] = b4[tid]; sB[4 * HID + tid] = gamma[tid]; sB[5 * HID + tid] = beta[tid];
        }
    }
    __syncthreads();
    const int e = blockIdx.x * 256 + tid;
    if (e >= E) return;
    float h0[IN_DIM];
    {
        const float4* xv = (const float4*)(x + (size_t)e * IN_DIM);
        #pragma unroll
        for (int c = 0; c < 8; ++c) {
            const float4 v = xv[c];
            h0[c * 4 + 0] = v.x; h0[c * 4 + 1] = v.y; h0[c * 4 + 2] = v.z; h0[c * 4 + 3] = v.w;
        }
    }
    float a[HID], h[HID];
    #pragma unroll
    for (int j = 0; j < HID; ++j) a[j] = sB[j];
    #pragma unroll
    for (int k = 0; k < IN_DIM; ++k) {
        const float hk = h0[k];
        #pragma unroll
        for (int j = 0; j < HID; ++j) a[j] = fmaf(hk, sW1[k * HID + j], a[j]);
    }
    #pragma unroll
    for (int j = 0; j < HID; ++j) h[j] = a[j] > 0.f ? a[j] : 0.f;
    #pragma unroll
    for (int j = 0; j < HID; ++j) a[j] = sB[HID + j];
    #pragma unroll
    for (int k = 0; k < HID; ++k) {
        const float hk = h[k];
        #pragma unroll
        for (int j = 0; j < HID; ++j) a[j] = fmaf(hk, sW2[k * HID + j], a[j]);
    }
    #pragma unroll
    for (int j = 0; j < HID; ++j) h[j] = a[j] > 0.f ? a[j] : 0.f;
    #pragma unroll
    for (int j = 0; j < HID; ++j) a[j] = sB[2 * HID + j];
    #pragma unroll
    for (int k = 0; k < HID; ++k) {
        const float hk = h[k];
        #pragma unroll
        for (int j = 0; j < HID; ++j) a[j] = fmaf(hk, sW3[k * HID + j], a[j]);
    }
    #pragma unroll
    for (int j = 0; j < HID; ++j) h[j] = a[j] > 0.f ? a[j] : 0.f;
    #pragma unroll
    for (int j = 0; j < HID; ++j) a[j] = sB[3 * HID + j];
    #pragma unroll
    for (int k = 0; k < HID; ++k) {
        const float hk = h[k];
        #pragma unroll
        for (int j = 0; j < HID; ++j) a[j] = fmaf(hk, sW4[k * HID + j], a[j]);
    }
    float s = 0.f;
    #pragma unroll
    for (int j = 0; j < HID; ++j) s += a[j];
    const float mu = s * (1.0f / HID);
    float s2 = 0.f;
    #pragma unroll
    for (int j = 0; j < HID; ++j) { const float d = a[j] - mu; s2 += d * d; }
    const float inv = rsqrtf(s2 * (1.0f / HID) + LN_EPS);
    #pragma unroll
    for (int j = 0; j < HID; ++j)
        a[j] = sB[4 * HID + j] * ((a[j] - mu) * inv) + sB[5 * HID + j];
    {
        float4* oe = (float4*)(out_edge + (size_t)e * HID);
        #pragma unroll
        for (int c = 0; c < 16; ++c)
            oe[c] = make_float4(a[c * 4], a[c * 4 + 1], a[c * 4 + 2], a[c * 4 + 3]);
    }
    const bool idx64 = sniff_idx64(idx);
    int na, nb;
    if (idx64) { na = idx[4 * (size_t)e]; nb = idx[4 * (size_t)e + 2]; }
    else       { na = idx[2 * (size_t)e]; nb = idx[2 * (size_t)e + 1]; }
    na = min(max(na, 0), N - 1);
    nb = min(max(nb, 0), N - 1);
    float* pa = node_acc + (size_t)na * HID;
    float* pb = node_acc + (size_t)nb * HID;
    #pragma unroll
    for (int j = 0; j < HID; ++j) {
        unsafeAtomicAdd(pa + j, a[j]);
        unsafeAtomicAdd(pb + j, a[j]);
    }
}

// one 64-lane wave per node; lane = feature index
__global__ __launch_bounds__(256) void gather_nodes(
    const int* __restrict__ off, const int* __restrict__ elist,
    const float* __restrict__ edge_feat, float* __restrict__ out_node, int N)
{
    const int wv = (blockIdx.x * 256 + threadIdx.x) >> 6;
    const int lane = threadIdx.x & 63;
    if (wv >= N) return;
    const int start = (wv == 0) ? 0 : off[wv - 1];
    const int end = off[wv];
    float s = 0.f;
    int i = start;
    for (; i + 4 <= end; i += 4) {
        const int e0 = elist[i], e1 = elist[i + 1], e2 = elist[i + 2], e3 = elist[i + 3];
        const float v0 = edge_feat[(size_t)e0 * HID + lane];
        const float v1 = edge_feat[(size_t)e1 * HID + lane];
        const float v2 = edge_feat[(size_t)e2 * HID + lane];
        const float v3 = edge_feat[(size_t)e3 * HID + lane];
        s += v0; s += v1; s += v2; s += v3;
    }
    for (; i < end; ++i) s += edge_feat[(size_t)elist[i] * HID + lane];
    out_node[(size_t)wv * HID + lane] = s;
}

extern "C" void kernel_launch(void* const* d_in, const int* in_sizes, int n_in,
                              void* d_out, int out_size, void* d_ws, size_t ws_size,
                              hipStream_t stream) {
    const float* x     = (const float*)d_in[0];
    const int*   idx   = (const int*)d_in[1];
    const float* W1    = (const float*)d_in[3];
    const float* b1    = (const float*)d_in[4];
    const float* W2    = (const float*)d_in[5];
    const float* b2    = (const float*)d_in[6];
    const float* W3    = (const float*)d_in[7];
    const float* b3    = (const float*)d_in[8];
    const float* W4    = (const float*)d_in[9];
    const float* b4    = (const float*)d_in[10];
    const float* gamma = (const float*)d_in[11];
    const float* beta  = (const float*)d_in[12];

    const int E = in_sizes[0] / IN_DIM;
    const int N = out_size / HID - E;

    float* out_node = (float*)d_out;
    float* out_edge = out_node + (size_t)N * HID;

    const size_t packB = 14336 * sizeof(ush);        // 28 KB
    const size_t need = packB + (size_t)N * sizeof(int) + (size_t)2 * E * sizeof(int);

    if (ws_size >= need) {
        ush* pack  = (ush*)d_ws;
        int* off   = (int*)((char*)d_ws + packB);
        int* elist = off + N;

        pack_weights<<<(14336 + 255) / 256, 256, 0, stream>>>(W1, W2, W3, W4, pack);
        zero_i32<<<(N + 255) / 256, 256, 0, stream>>>(off, N);
        count_deg<<<(2 * E + 255) / 256, 256, 0, stream>>>(idx, off, E, N);
        scan_excl<<<1, 1024, 0, stream>>>(off, N);
        fill_csr<<<(E + 255) / 256, 256, 0, stream>>>(idx, off, elist, E, N);
        mlp_ln_mfma<<<(E + 127) / 128, 256, 0, stream>>>(
            x, pack, b1, b2, b3, b4, gamma, beta, out_edge, E);
        gather_nodes<<<(N * 64 + 255) / 256, 256, 0, stream>>>(
            off, elist, out_edge, out_node, N);
    } else {
        const int n16 = (int)(((size_t)N * HID * sizeof(float)) / 16);
        zero16<<<(n16 + 255) / 256, 256, 0, stream>>>((uint4*)out_node, n16);
        mlp_ln_scatter_fb<<<(E + 255) / 256, 256, 0, stream>>>(
            x, idx, W1, b1, W2, b2, W3, b3, W4, b4, gamma, beta,
            out_edge, out_node, E, N);
    }
}